// Round 8
// baseline (944.973 us; speedup 1.0000x reference)
//
#include <hip/hip_runtime.h>
#include <stdint.h>

// VQ-VAE codebook argmin, f32 in / f32 out.
// R13: register-direct W. R12 post-mortem: removing ALL barriers bought only
// 2.5% -> the stall is attached to staging itself. Theory: hipcc cannot prove
// in-loop global_load_lds (a vmcnt-counted LDS-WRITING op) doesn't alias the
// ds_read sources, so it inserts its own s_waitcnt vmcnt(0) before each
// step's ds_reads, draining the just-issued prefetch every step (the ~1100cyc
// stall all rounds share). Fix: W never touches LDS. The B-fragment per-lane
// address equals the STAGE_W+ds_read round-trip (HW-proven mapping), so load
// W straight into registers (bhalf8_t = global_load_dwordx4) in a 4-deep
// ring wr[4][2]; inner k2 loop fully unrolled -> static indices (rule-20).
// Register loads carry precise per-register deps -> compiler emits counted
// vmcnt for exactly the consumed buffer; K-loop has ZERO LDS writes so A
// ds_reads need only lgkmcnt (m97-proven). load(st+4) issued after
// compute(st): ~3 compute-steps (~450cyc) cover W's L2 latency.
// Z stationary in LDS (64KB, fragment-major, R9-proven) -> 2 blocks/CU.
// W cols wave-private (32/wave) -> traffic unchanged, W slice L2-resident
// per XCD (super=b&3, XCD=b&7). Ranking: per-lane-column top-2 over (tl,fn),
// id=tl*2+fn, 128-key scan (R12 structure, 61K conflicts = fine).
// k_exact numerics unchanged (16 exact-f32 candidates, R4-proven anchor).

#define B_ROWS 32768
#define DIM    512
#define KCODES 8192
#define SUPERS 4
#define TILES  16   // per super: 16 tiles * 128 = 2048 codes
#define ZROWS  64   // Z rows per block (stationary in LDS, full K)
#define NSTEP  256  // TILES * 16 K-steps (BK=32)

typedef short bhalf8_t __attribute__((ext_vector_type(8)));
typedef float f32x4_t  __attribute__((ext_vector_type(4)));

__device__ __forceinline__ float b2f(unsigned short u) {
    return __uint_as_float(((unsigned int)u) << 16);
}
__device__ __forceinline__ unsigned short f2b(float f) {  // RNE
    unsigned int x = __float_as_uint(f);
    return (unsigned short)((x + 0x7FFFu + ((x >> 16) & 1u)) >> 16);
}
__device__ __forceinline__ void gl_lds16(const void* g, void* l) {
    __builtin_amdgcn_global_load_lds(
        (const __attribute__((address_space(1))) unsigned int*)g,
        (__attribute__((address_space(3))) unsigned int*)l, 16, 0, 0);
}

// ---------- K0: f32 -> bf16 (hi only) ----------
__global__ __launch_bounds__(256) void k_split(const float4* __restrict__ src,
                                               ushort4* __restrict__ dst, int n4) {
    int i = blockIdx.x * 256 + threadIdx.x;
    int stride = gridDim.x * 256;
    for (; i < n4; i += stride) {
        float4 v = src[i];
        ushort4 h;
        h.x = f2b(v.x); h.y = f2b(v.y); h.z = f2b(v.z); h.w = f2b(v.w);
        dst[i] = h;
    }
}

// ---------- K1: numpy-pairwise-emulated row sum of squares (R4-proven) ----------
__global__ __launch_bounds__(256) void k_pairsq(const float* __restrict__ X,
                                                float* __restrict__ out, int nrows) {
    int wid = threadIdx.x >> 6, lane = threadIdx.x & 63;
    int r = blockIdx.x * 4 + wid;
    if (r >= nrows) return;
    int b = lane >> 3, j = lane & 7;
    float acc = 0.f;
    if (b < 4) {
        const float* x = X + (size_t)r * DIM + b * 128 + j;
        float v = x[0];
        acc = __fmul_rn(v, v);
        for (int i = 1; i < 16; i++) {
            float w = x[8 * i];
            acc = __fadd_rn(acc, __fmul_rn(w, w));
        }
    }
    float t = __fadd_rn(acc, __shfl_xor(acc, 1));
    t = __fadd_rn(t, __shfl_xor(t, 2));
    t = __fadd_rn(t, __shfl_xor(t, 4));
    float u = __fadd_rn(t, __shfl_xor(t, 8));
    u = __fadd_rn(u, __shfl_xor(u, 16));
    if (lane == 0) out[r] = u;
}

// ---------- K2: Z-stationary GEMM, register-direct W, 4-deep pipeline ----------
// LDS (64KB): Z only — 16 fragment-major 32-k slices of 64 rows.
// Fragment-major slice (HW-verified R6-R12): element (row, kseg) at byte
//   (row>>4)*1024 + kseg*256 + (row&15)*16
// A-frag: af[f] = zl + ks*4096 + f*1024 + lane*16 (contiguous 1024B wave
// read, conflict-free). B-frag loaded DIRECTLY to registers:
//   bf[f][lane] = Wh[(nt + f*16 + (lane&15))*512 + (st&15)*32 + (lane>>4)*8]
// (identical mapping to the old STAGE_W+ds_read round-trip, LDS cut out).
__device__ __forceinline__ void loadW(const unsigned short* __restrict__ Wh,
                                      int super, int w, int lane15, int q, int st,
                                      bhalf8_t& o0, bhalf8_t& o1) {
    const int nt = super * 2048 + (st >> 4) * 128 + w * 32;
    const unsigned short* p = Wh + (size_t)(nt + lane15) * DIM + (st & 15) * 32 + q * 8;
    o0 = *(const bhalf8_t*)(p);
    o1 = *(const bhalf8_t*)(p + 16 * DIM);
}

__device__ __forceinline__ void computeA(const unsigned char* zl, int ks, int lane,
                                         bhalf8_t b0, bhalf8_t b1,
                                         f32x4_t acc[4][2]) {
    bhalf8_t af[4];
#pragma unroll
    for (int f = 0; f < 4; f++)
        af[f] = *(const bhalf8_t*)(zl + ks * 4096 + f * 1024 + lane * 16);
#pragma unroll
    for (int fm = 0; fm < 4; fm++) {
        acc[fm][0] = __builtin_amdgcn_mfma_f32_16x16x32_bf16(af[fm], b0, acc[fm][0], 0, 0, 0);
        acc[fm][1] = __builtin_amdgcn_mfma_f32_16x16x32_bf16(af[fm], b1, acc[fm][1], 0, 0, 0);
    }
}

__global__ __launch_bounds__(256) void k_argmin(const unsigned short* __restrict__ Zh,
                                                const unsigned short* __restrict__ Wh,
                                                const float* __restrict__ ww,
                                                float2* __restrict__ part) {
    __shared__ alignas(16) unsigned char smem[65536];
    const int tid = threadIdx.x;
    const int lane = tid & 63, w = tid >> 6;
    const int lane15 = lane & 15, q = lane >> 4;
    const int b = blockIdx.x;
    const int super = b & 3;          // XCD = b&7 -> one 2MB W-slice per XCD (L2-resident)
    const int rb = (b >> 2) * ZROWS;

    unsigned char* zl = smem;         // 64KB Z

    // ---- Z prologue: stage 64 rows x 512 k once (16 gl_lds16 per thread) ----
    // slot s = i*256 + tid; dest byte = s*16 (linear, lane-contiguous).
    // decode: ks=s>>8, g=(s>>6)&3, kseg=(s>>4)&3, m=s&15; row=g*16+m.
    {
        const int m = tid & 15;
        const int kseg8 = ((tid >> 4) & 3) << 3;
#pragma unroll
        for (int i = 0; i < 16; i++) {
            const int s = i * 256 + tid;
            const int ks = s >> 8;
            const int g = (s >> 6) & 3;
            gl_lds16(Zh + (size_t)(rb + g * 16 + m) * DIM + ks * 32 + kseg8,
                     zl + s * 16);
        }
    }

    uint32_t p1[4][4], p2[4][4];
#pragma unroll
    for (int i = 0; i < 4; i++)
#pragma unroll
        for (int jj = 0; jj < 4; jj++) { p1[i][jj] = 0xFFFFFFFFu; p2[i][jj] = 0xFFFFFFFFu; }

    // prime the 4-deep W register ring (steps 0..3)
    bhalf8_t wr[4][2];
#pragma unroll
    for (int p = 0; p < 4; p++)
        loadW(Wh, super, w, lane15, q, p, wr[p][0], wr[p][1]);

    __syncthreads();   // Z staged (compiler drains the Z gl_lds16 vmcnt here)

    for (int tl = 0; tl < TILES; ++tl) {
        const int nt = super * 2048 + tl * 128;
        float cb0 = ww[nt + w * 32 + lane15] + 0.5f;
        float cb1 = ww[nt + w * 32 + 16 + lane15] + 0.5f;

        f32x4_t acc[4][2];
#pragma unroll
        for (int i = 0; i < 4; i++)
#pragma unroll
            for (int jj = 0; jj < 2; jj++) acc[i][jj] = (f32x4_t){0.f, 0.f, 0.f, 0.f};

#pragma unroll
        for (int k2 = 0; k2 < 16; ++k2) {
            const int st = tl * 16 + k2;
            computeA(zl, k2, lane, wr[k2 & 3][0], wr[k2 & 3][1], acc);
            if (st + 4 < NSTEP)   // uniform guard; skip only for the last 4 steps
                loadW(Wh, super, w, lane15, q, st + 4, wr[k2 & 3][0], wr[k2 & 3][1]);
        }

        // epilogue: s' = (ww[n]+0.5) - 2*dot (positive => float bits monotonic);
        // pack: high-25 bits | id = tl*2+fn (<32, fits 7-bit field). Strict '<'
        // ascending (tl,fn) insert => smaller n wins ties within a lane-column.
#pragma unroll
        for (int fm = 0; fm < 4; fm++)
#pragma unroll
            for (int r = 0; r < 4; r++)
#pragma unroll
                for (int fn = 0; fn < 2; fn++) {
                    float sv = fmaf(-2.0f, acc[fm][fn][r], fn ? cb1 : cb0);
                    uint32_t pk = (__float_as_uint(sv) & 0xFFFFFF80u) | (uint32_t)(tl * 2 + fn);
                    if (pk < p1[fm][r]) { p2[fm][r] = p1[fm][r]; p1[fm][r] = pk; }
                    else if (pk < p2[fm][r]) { p2[fm][r] = pk; }
                }
    }

    // per-row top-4 of 128 packed keys via LDS (reuses Z region; stride 130
    // elements -> scan banks (2*row+e)%32: 2-way conflict = free, m136)
    __syncthreads();
    uint32_t* keys = (uint32_t*)smem;   // [64 rows][stride 130]: 128 keys + pad
#pragma unroll
    for (int fm = 0; fm < 4; fm++)
#pragma unroll
        for (int r = 0; r < 4; r++) {
            int row = fm * 16 + q * 4 + r;   // C/D row = (lane>>4)*4 + reg
            int sp = w * 16 + lane15;        // slot-position 0..63
            keys[row * 130 + sp * 2 + 0] = p1[fm][r];
            keys[row * 130 + sp * 2 + 1] = p2[fm][r];
        }
    __syncthreads();
    if (tid < ZROWS) {
        int row = tid;
        int rglob = rb + row;
        for (int s = 0; s < 4; s++) {
            uint32_t bk = 0xFFFFFFFFu; int be = 0;
            for (int e = 0; e < 128; e++) {
                uint32_t k = keys[row * 130 + e];
                if (k < bk) { bk = k; be = e; }
            }
            int sp = be >> 1;                 // w*16 + lane15
            int id = (int)(bk & 127u);        // tl*2 + fn
            int n = super * 2048 + (id >> 1) * 128 + (sp >> 4) * 32 + (id & 1) * 16 + (sp & 15);
            part[((size_t)rglob * SUPERS + super) * 4 + s] =
                make_float2(__uint_as_float(bk), __int_as_float(n));
            keys[row * 130 + be] = 0xFFFFFFFFu;  // consume
        }
    }
}

// ---------- K3: exact numpy-f32 re-rank of 16 candidates, outputs (R4-proven) ----------
__global__ __launch_bounds__(256) void k_exact(const float* __restrict__ Zf,
                                               const float* __restrict__ Wf,
                                               const float2* __restrict__ part,
                                               const float* __restrict__ zz,
                                               const float* __restrict__ ww,
                                               float* __restrict__ outf,
                                               float* __restrict__ lossp) {
    __shared__ float wsum[4];
    int wid = threadIdx.x >> 6, lane = threadIdx.x & 63;
    int r = blockIdx.x * 4 + wid;
    int c = lane >> 2, j = lane & 3;   // candidate 0..15, SSE lane 0..3

    // candidates: 4 supers x top-4
    float2 P = part[((size_t)r * SUPERS + (c >> 2)) * 4 + (c & 3)];
    int n = __float_as_int(P.y);
    n = min(max(n, 0), KCODES - 1);

    // numpy einsum baseline-SIMD: 4 stride-4 f32 accumulators (mul+add, no FMA)
    const float* zp = Zf + (size_t)r * DIM + j;
    const float* wp = Wf + (size_t)n * DIM + j;
    float acc = 0.f;
    for (int i = 0; i < 128; i++)
        acc = __fadd_rn(acc, __fmul_rn(zp[4 * i], wp[4 * i]));
    float t = __fadd_rn(acc, __shfl_xor(acc, 1));
    t = __fadd_rn(t, __shfl_xor(t, 2));
    float dot = __shfl(t, c * 4);

    float t1 = __fadd_rn(zz[r], ww[n]);
    float t2 = __fmul_rn(2.0f, dot);
    float d2 = __fadd_rn(t1, -t2);

    float bd = (j == 0) ? d2 : 3.4e38f;
    int   bn = (j == 0) ? n  : 0x7FFFFFFF;
#pragma unroll
    for (int off = 32; off; off >>= 1) {
        float od = __shfl_xor(bd, off);
        int   on = __shfl_xor(bn, off);
        if (od < bd || (od == bd && on < bn)) { bd = od; bn = on; }
    }
    int idx = bn;

    float4 wa = *(const float4*)(Wf + (size_t)idx * DIM + lane * 8);
    float4 wb = *(const float4*)(Wf + (size_t)idx * DIM + lane * 8 + 4);
    float4 za = *(const float4*)(Zf + (size_t)r   * DIM + lane * 8);
    float4 zb = *(const float4*)(Zf + (size_t)r   * DIM + lane * 8 + 4);
    *(float4*)(outf + (size_t)r * DIM + lane * 8)     = wa;
    *(float4*)(outf + (size_t)r * DIM + lane * 8 + 4) = wb;
    float d0 = za.x - wa.x, d1 = za.y - wa.y, dd2 = za.z - wa.z, d3 = za.w - wa.w;
    float d4 = zb.x - wb.x, d5 = zb.y - wb.y, d6 = zb.z - wb.z, d7 = zb.w - wb.w;
    float ls = d0*d0 + d1*d1 + dd2*dd2 + d3*d3 + d4*d4 + d5*d5 + d6*d6 + d7*d7;
#pragma unroll
    for (int off = 32; off; off >>= 1) ls += __shfl_xor(ls, off);
    if (lane == 0) {
        outf[(size_t)B_ROWS * DIM + r] = (float)idx;
        wsum[wid] = ls;
    }
    __syncthreads();
    if (threadIdx.x == 0) lossp[blockIdx.x] = wsum[0] + wsum[1] + wsum[2] + wsum[3];
}

// ---------- K4: loss reduction ----------
__global__ __launch_bounds__(256) void k_loss(const float* __restrict__ lossp,
                                              float* __restrict__ outf) {
    __shared__ float sm[256];
    float a = 0.f;
    for (int i = threadIdx.x; i < 8192; i += 256) a += lossp[i];
    sm[threadIdx.x] = a;
    __syncthreads();
    for (int s = 128; s; s >>= 1) {
        if (threadIdx.x < s) sm[threadIdx.x] += sm[threadIdx.x + s];
        __syncthreads();
    }
    if (threadIdx.x == 0)
        outf[(size_t)B_ROWS * DIM + B_ROWS] = 1.25f * sm[0] / 16777216.0f;
}

extern "C" void kernel_launch(void* const* d_in, const int* in_sizes, int n_in,
                              void* d_out, int out_size, void* d_ws, size_t ws_size,
                              hipStream_t stream) {
    (void)in_sizes; (void)n_in; (void)out_size; (void)ws_size;
    const float* Zf = (const float*)d_in[0];   // [32768, 512] f32
    const float* Wf = (const float*)d_in[1];   // [8192, 512]  f32
    float* outf = (float*)d_out;               // f32: z_q | indices | loss

    // bf16 scratch inside d_out's z_q region (64 MB): Zh 32MB @0 | Wh 8MB @32MB.
    // k_exact overwrites it with the final z_q (k_argmin has completed by then).
    unsigned short* Zh = (unsigned short*)d_out;
    unsigned short* Wh = (unsigned short*)((char*)d_out + (32ull << 20));

    // ws (4.39 MB, proven): ww 32KB @0 | zz 128KB @32K | lossp 32KB @160K | part 4MB @192K
    // part layout: [row][super(4)][4 entries] float2 = 4MB.
    float*  ww    = (float*)d_ws;
    float*  zz    = (float*)((char*)d_ws + 32768);
    float*  lossp = (float*)((char*)d_ws + 163840);
    float2* partp = (float2*)((char*)d_ws + 196608);

    k_split<<<1024, 256, 0, stream>>>((const float4*)Zf, (ushort4*)Zh, B_ROWS * DIM / 4);
    k_split<<<512,  256, 0, stream>>>((const float4*)Wf, (ushort4*)Wh, KCODES * DIM / 4);
    k_pairsq<<<KCODES / 4, 256, 0, stream>>>(Wf, ww, KCODES);
    k_pairsq<<<B_ROWS / 4, 256, 0, stream>>>(Zf, zz, B_ROWS);
    k_argmin<<<(B_ROWS / ZROWS) * SUPERS, 256, 0, stream>>>(Zh, Wh, ww, partp);
    k_exact<<<B_ROWS / 4, 256, 0, stream>>>(Zf, Wf, partp, zz, ww, outf, lossp);
    k_loss<<<1, 256, 0, stream>>>(lossp, outf);
}

// Round 9
// 844.436 us; speedup vs baseline: 1.1191x; 1.1191x over previous
//
#include <hip/hip_runtime.h>
#include <stdint.h>

// VQ-VAE codebook argmin, f32 in / f32 out.
// R14: occupancy x2 at constant LDS. R5-R13 meta-result: every sync variant
// (2-barrier R5/R9, 1-barrier R10, 0-barrier R12, reg-ring R13) lands
// 525-675us; traffic 1.1GB vs 100MB doesn't matter either. The variable that
// tracks time is waves/CU: all rounds had <=8 (2/SIMD), step-slot ~1290cyc vs
// ~400cyc HW floor = unhidden ds_read/L2 latency. Fix: 512-thread blocks
// (8 waves), wave-tile 32x32, SAME 80KB LDS (Z 64KB stationary + shared W
// 8KB dbuf, R10-proven 2 blocks/CU) -> 16 waves/CU = 4/SIMD. Same grid, same
// MFMA count, same W traffic. Per-wave VGPR DROPS (acc 16, p1/p2 16 vs 32/32)
// -> ~95 <= 128 so the 16-wave budget holds (R13 lesson inverted: stay under
// the m69 cliff). Barrier drain now hidden by co-resident block's 8 waves.
// Ranking: per-lane-column top-2 over (tl,fn), id=tl*2+fn, 128-key scan,
// stride-130 keys (R12-proven). k_exact numerics unchanged (16 exact-f32
// candidates, R4-proven anchor).

#define B_ROWS 32768
#define DIM    512
#define KCODES 8192
#define SUPERS 4
#define TILES  16   // per super: 16 tiles * 128 = 2048 codes
#define ZROWS  64   // Z rows per block (stationary in LDS, full K)
#define NSTEP  256  // TILES * 16 K-steps (BK=32)

typedef short bhalf8_t __attribute__((ext_vector_type(8)));
typedef float f32x4_t  __attribute__((ext_vector_type(4)));

__device__ __forceinline__ float b2f(unsigned short u) {
    return __uint_as_float(((unsigned int)u) << 16);
}
__device__ __forceinline__ unsigned short f2b(float f) {  // RNE
    unsigned int x = __float_as_uint(f);
    return (unsigned short)((x + 0x7FFFu + ((x >> 16) & 1u)) >> 16);
}
__device__ __forceinline__ void gl_lds16(const void* g, void* l) {
    __builtin_amdgcn_global_load_lds(
        (const __attribute__((address_space(1))) unsigned int*)g,
        (__attribute__((address_space(3))) unsigned int*)l, 16, 0, 0);
}

// ---------- K0: f32 -> bf16 (hi only) ----------
__global__ __launch_bounds__(256) void k_split(const float4* __restrict__ src,
                                               ushort4* __restrict__ dst, int n4) {
    int i = blockIdx.x * 256 + threadIdx.x;
    int stride = gridDim.x * 256;
    for (; i < n4; i += stride) {
        float4 v = src[i];
        ushort4 h;
        h.x = f2b(v.x); h.y = f2b(v.y); h.z = f2b(v.z); h.w = f2b(v.w);
        dst[i] = h;
    }
}

// ---------- K1: numpy-pairwise-emulated row sum of squares (R4-proven) ----------
__global__ __launch_bounds__(256) void k_pairsq(const float* __restrict__ X,
                                                float* __restrict__ out, int nrows) {
    int wid = threadIdx.x >> 6, lane = threadIdx.x & 63;
    int r = blockIdx.x * 4 + wid;
    if (r >= nrows) return;
    int b = lane >> 3, j = lane & 7;
    float acc = 0.f;
    if (b < 4) {
        const float* x = X + (size_t)r * DIM + b * 128 + j;
        float v = x[0];
        acc = __fmul_rn(v, v);
        for (int i = 1; i < 16; i++) {
            float w = x[8 * i];
            acc = __fadd_rn(acc, __fmul_rn(w, w));
        }
    }
    float t = __fadd_rn(acc, __shfl_xor(acc, 1));
    t = __fadd_rn(t, __shfl_xor(t, 2));
    t = __fadd_rn(t, __shfl_xor(t, 4));
    float u = __fadd_rn(t, __shfl_xor(t, 8));
    u = __fadd_rn(u, __shfl_xor(u, 16));
    if (lane == 0) out[r] = u;
}

// ---------- K2: Z-stationary GEMM, 8 waves, shared W dbuf, 1 barrier/step ----------
// LDS (80KB): [0,64K) Z: 16 fragment-major 32-k slices of 64 rows
//             [64K,72K) W buf0 | [72K,80K) W buf1 (128 codes x 32k each)
// Fragment-major slice (HW-verified R6-R13): element (row, kseg) at byte
//   (row>>4)*1024 + kseg*256 + (row&15)*16
// Wave-tile 32x32: wm = w>>2 (rows), wn = w&3 (cols). Wave reads
//   af[f] = zl + ks*4096 + (wm*2+f)*1024 + lane*16      (contiguous 1024B)
//   bf[f] = wbuf + (wn*2+f)*1024 + lane*16              (contiguous 1024B)
// global_load_lds dest LINEAR; layout permutation on the per-lane GLOBAL
// source address (both-sides-or-neither rule).
__device__ __forceinline__ void compute_ks(const unsigned char* zl, int ks,
                                           const unsigned char* wbuf,
                                           int wm, int wn, int lane,
                                           f32x4_t acc[2][2]) {
    bhalf8_t af[2], bf[2];
#pragma unroll
    for (int f = 0; f < 2; f++)
        af[f] = *(const bhalf8_t*)(zl + ks * 4096 + (wm * 2 + f) * 1024 + lane * 16);
#pragma unroll
    for (int f = 0; f < 2; f++)
        bf[f] = *(const bhalf8_t*)(wbuf + (wn * 2 + f) * 1024 + lane * 16);
#pragma unroll
    for (int fm = 0; fm < 2; fm++)
#pragma unroll
        for (int fn = 0; fn < 2; fn++)
            acc[fm][fn] = __builtin_amdgcn_mfma_f32_16x16x32_bf16(af[fm], bf[fn], acc[fm][fn], 0, 0, 0);
}

__global__ __launch_bounds__(512) void k_argmin(const unsigned short* __restrict__ Zh,
                                                const unsigned short* __restrict__ Wh,
                                                const float* __restrict__ ww,
                                                float2* __restrict__ part) {
    __shared__ alignas(16) unsigned char smem[81920];
    const int tid = threadIdx.x;
    const int lane = tid & 63, w = tid >> 6;
    const int wm = w >> 2, wn = w & 3;
    const int lane15 = lane & 15, q = lane >> 4;
    const int b = blockIdx.x;
    const int super = b & 3;          // XCD = b&7 -> one 2MB W-slice per XCD (L2-resident)
    const int rb = (b >> 2) * ZROWS;

    unsigned char* zl  = smem;                    // 64KB Z
    unsigned char* wl0 = smem + 65536;            // 8KB W buf0
    unsigned char* wl1 = smem + 65536 + 8192;     // 8KB W buf1

    // ---- Z prologue: stage 64 rows x 512 k once (8 gl_lds16 per thread) ----
    // slot s = i*512 + tid; dest byte = s*16 (linear, lane-contiguous).
    // decode: ks=s>>8, g=(s>>6)&3, kseg=(s>>4)&3, m=s&15; row=g*16+m.
    {
        const int m = tid & 15;
        const int kseg8 = ((tid >> 4) & 3) << 3;
#pragma unroll
        for (int i = 0; i < 8; i++) {
            const int s = i * 512 + tid;
            const int ks = s >> 8;
            const int g = (s >> 6) & 3;
            gl_lds16(Zh + (size_t)(rb + g * 16 + m) * DIM + ks * 32 + kseg8,
                     zl + s * 16);
        }
    }

    // Shared W stage: 8KB/step = 512 threads x one 16B slot each.
    // slot s = tid: col = (s>>6)*16 + (s&15) in [0,128), kseg = (s>>4)&3.
    const int colO = ((tid >> 6) << 4) | (tid & 15);
    const int kO   = ((tid >> 4) & 3) << 3;
    const int dst0 = tid * 16;
#define STAGE_W(ST, WB)                                                     \
    do {                                                                    \
        const int _nt = super * 2048 + ((ST) >> 4) * 128;                   \
        const int _kg = ((ST) & 15) * 32 + kO;                              \
        gl_lds16(Wh + (size_t)(_nt + colO) * DIM + _kg, (WB) + dst0);       \
    } while (0)

    uint32_t p1[2][4], p2[2][4];
#pragma unroll
    for (int i = 0; i < 2; i++)
#pragma unroll
        for (int jj = 0; jj < 4; jj++) { p1[i][jj] = 0xFFFFFFFFu; p2[i][jj] = 0xFFFFFFFFu; }

    STAGE_W(0, wl0);
    __syncthreads();   // Z + W step-0 staged (compiler drains vmcnt before barrier)

    for (int tl = 0; tl < TILES; ++tl) {
        const int nt = super * 2048 + tl * 128;
        float cb0 = ww[nt + wn * 32 + lane15] + 0.5f;
        float cb1 = ww[nt + wn * 32 + 16 + lane15] + 0.5f;

        f32x4_t acc[2][2];
#pragma unroll
        for (int i = 0; i < 2; i++)
#pragma unroll
            for (int jj = 0; jj < 2; jj++) acc[i][jj] = (f32x4_t){0.f, 0.f, 0.f, 0.f};

        for (int k2 = 0; k2 < 16; k2 += 2) {
            const int st = tl * 16 + k2;
            // even: stage st+1 -> buf1 (buf1 readers finished at prior odd
            // sync), compute buf0; sync drains st+1 (issued a compute ago).
            STAGE_W(st + 1, wl1);
            compute_ks(zl, k2, wl0, wm, wn, lane, acc);
            __syncthreads();
            // odd: stage st+2 -> buf0 (readers done at even sync), compute
            // buf1; sync drains st+2 before next even reads buf0.
            if (st + 2 < NSTEP) STAGE_W(st + 2, wl0);
            compute_ks(zl, k2 + 1, wl1, wm, wn, lane, acc);
            __syncthreads();
        }

        // epilogue: s' = (ww[n]+0.5) - 2*dot (positive => float bits monotonic);
        // pack: high-25 bits | id = tl*2+fn (<32, fits 7-bit field). Strict '<'
        // ascending (tl,fn) insert => smaller n wins ties within a lane-column.
#pragma unroll
        for (int fm = 0; fm < 2; fm++)
#pragma unroll
            for (int r = 0; r < 4; r++)
#pragma unroll
                for (int fn = 0; fn < 2; fn++) {
                    float sv = fmaf(-2.0f, acc[fm][fn][r], fn ? cb1 : cb0);
                    uint32_t pk = (__float_as_uint(sv) & 0xFFFFFF80u) | (uint32_t)(tl * 2 + fn);
                    if (pk < p1[fm][r]) { p2[fm][r] = p1[fm][r]; p1[fm][r] = pk; }
                    else if (pk < p2[fm][r]) { p2[fm][r] = pk; }
                }
    }
#undef STAGE_W

    // per-row top-4 of 128 packed keys via LDS (reuses Z region; stride 130
    // elements -> scan banks (2*row+e)%32: 2-way conflict = free, m136)
    __syncthreads();
    uint32_t* keys = (uint32_t*)smem;   // [64 rows][stride 130]: 128 keys + pad
#pragma unroll
    for (int fm = 0; fm < 2; fm++)
#pragma unroll
        for (int r = 0; r < 4; r++) {
            int row = wm * 32 + fm * 16 + q * 4 + r;  // C/D row = (lane>>4)*4 + reg
            int sp = wn * 16 + lane15;                // slot-position 0..63
            keys[row * 130 + sp * 2 + 0] = p1[fm][r];
            keys[row * 130 + sp * 2 + 1] = p2[fm][r];
        }
    __syncthreads();
    if (tid < ZROWS) {
        int row = tid;
        int rglob = rb + row;
        for (int s = 0; s < 4; s++) {
            uint32_t bk = 0xFFFFFFFFu; int be = 0;
            for (int e = 0; e < 128; e++) {
                uint32_t k = keys[row * 130 + e];
                if (k < bk) { bk = k; be = e; }
            }
            int sp = be >> 1;                 // wn*16 + lane15
            int id = (int)(bk & 127u);        // tl*2 + fn
            int n = super * 2048 + (id >> 1) * 128 + (sp >> 4) * 32 + (id & 1) * 16 + (sp & 15);
            part[((size_t)rglob * SUPERS + super) * 4 + s] =
                make_float2(__uint_as_float(bk), __int_as_float(n));
            keys[row * 130 + be] = 0xFFFFFFFFu;  // consume
        }
    }
}

// ---------- K3: exact numpy-f32 re-rank of 16 candidates, outputs (R4-proven) ----------
__global__ __launch_bounds__(256) void k_exact(const float* __restrict__ Zf,
                                               const float* __restrict__ Wf,
                                               const float2* __restrict__ part,
                                               const float* __restrict__ zz,
                                               const float* __restrict__ ww,
                                               float* __restrict__ outf,
                                               float* __restrict__ lossp) {
    __shared__ float wsum[4];
    int wid = threadIdx.x >> 6, lane = threadIdx.x & 63;
    int r = blockIdx.x * 4 + wid;
    int c = lane >> 2, j = lane & 3;   // candidate 0..15, SSE lane 0..3

    // candidates: 4 supers x top-4
    float2 P = part[((size_t)r * SUPERS + (c >> 2)) * 4 + (c & 3)];
    int n = __float_as_int(P.y);
    n = min(max(n, 0), KCODES - 1);

    // numpy einsum baseline-SIMD: 4 stride-4 f32 accumulators (mul+add, no FMA)
    const float* zp = Zf + (size_t)r * DIM + j;
    const float* wp = Wf + (size_t)n * DIM + j;
    float acc = 0.f;
    for (int i = 0; i < 128; i++)
        acc = __fadd_rn(acc, __fmul_rn(zp[4 * i], wp[4 * i]));
    float t = __fadd_rn(acc, __shfl_xor(acc, 1));
    t = __fadd_rn(t, __shfl_xor(t, 2));
    float dot = __shfl(t, c * 4);

    float t1 = __fadd_rn(zz[r], ww[n]);
    float t2 = __fmul_rn(2.0f, dot);
    float d2 = __fadd_rn(t1, -t2);

    float bd = (j == 0) ? d2 : 3.4e38f;
    int   bn = (j == 0) ? n  : 0x7FFFFFFF;
#pragma unroll
    for (int off = 32; off; off >>= 1) {
        float od = __shfl_xor(bd, off);
        int   on = __shfl_xor(bn, off);
        if (od < bd || (od == bd && on < bn)) { bd = od; bn = on; }
    }
    int idx = bn;

    float4 wa = *(const float4*)(Wf + (size_t)idx * DIM + lane * 8);
    float4 wb = *(const float4*)(Wf + (size_t)idx * DIM + lane * 8 + 4);
    float4 za = *(const float4*)(Zf + (size_t)r   * DIM + lane * 8);
    float4 zb = *(const float4*)(Zf + (size_t)r   * DIM + lane * 8 + 4);
    *(float4*)(outf + (size_t)r * DIM + lane * 8)     = wa;
    *(float4*)(outf + (size_t)r * DIM + lane * 8 + 4) = wb;
    float d0 = za.x - wa.x, d1 = za.y - wa.y, dd2 = za.z - wa.z, d3 = za.w - wa.w;
    float d4 = zb.x - wb.x, d5 = zb.y - wb.y, d6 = zb.z - wb.z, d7 = zb.w - wb.w;
    float ls = d0*d0 + d1*d1 + dd2*dd2 + d3*d3 + d4*d4 + d5*d5 + d6*d6 + d7*d7;
#pragma unroll
    for (int off = 32; off; off >>= 1) ls += __shfl_xor(ls, off);
    if (lane == 0) {
        outf[(size_t)B_ROWS * DIM + r] = (float)idx;
        wsum[wid] = ls;
    }
    __syncthreads();
    if (threadIdx.x == 0) lossp[blockIdx.x] = wsum[0] + wsum[1] + wsum[2] + wsum[3];
}

// ---------- K4: loss reduction ----------
__global__ __launch_bounds__(256) void k_loss(const float* __restrict__ lossp,
                                              float* __restrict__ outf) {
    __shared__ float sm[256];
    float a = 0.f;
    for (int i = threadIdx.x; i < 8192; i += 256) a += lossp[i];
    sm[threadIdx.x] = a;
    __syncthreads();
    for (int s = 128; s; s >>= 1) {
        if (threadIdx.x < s) sm[threadIdx.x] += sm[threadIdx.x + s];
        __syncthreads();
    }
    if (threadIdx.x == 0)
        outf[(size_t)B_ROWS * DIM + B_ROWS] = 1.25f * sm[0] / 16777216.0f;
}

extern "C" void kernel_launch(void* const* d_in, const int* in_sizes, int n_in,
                              void* d_out, int out_size, void* d_ws, size_t ws_size,
                              hipStream_t stream) {
    (void)in_sizes; (void)n_in; (void)out_size; (void)ws_size;
    const float* Zf = (const float*)d_in[0];   // [32768, 512] f32
    const float* Wf = (const float*)d_in[1];   // [8192, 512]  f32
    float* outf = (float*)d_out;               // f32: z_q | indices | loss

    // bf16 scratch inside d_out's z_q region (64 MB): Zh 32MB @0 | Wh 8MB @32MB.
    // k_exact overwrites it with the final z_q (k_argmin has completed by then).
    unsigned short* Zh = (unsigned short*)d_out;
    unsigned short* Wh = (unsigned short*)((char*)d_out + (32ull << 20));

    // ws (4.39 MB, proven): ww 32KB @0 | zz 128KB @32K | lossp 32KB @160K | part 4MB @192K
    // part layout: [row][super(4)][4 entries] float2 = 4MB.
    float*  ww    = (float*)d_ws;
    float*  zz    = (float*)((char*)d_ws + 32768);
    float*  lossp = (float*)((char*)d_ws + 163840);
    float2* partp = (float2*)((char*)d_ws + 196608);

    k_split<<<1024, 256, 0, stream>>>((const float4*)Zf, (ushort4*)Zh, B_ROWS * DIM / 4);
    k_split<<<512,  256, 0, stream>>>((const float4*)Wf, (ushort4*)Wh, KCODES * DIM / 4);
    k_pairsq<<<KCODES / 4, 256, 0, stream>>>(Wf, ww, KCODES);
    k_pairsq<<<B_ROWS / 4, 256, 0, stream>>>(Zf, zz, B_ROWS);
    k_argmin<<<(B_ROWS / ZROWS) * SUPERS, 512, 0, stream>>>(Zh, Wh, ww, partp);
    k_exact<<<B_ROWS / 4, 256, 0, stream>>>(Zf, Wf, partp, zz, ww, outf, lossp);
    k_loss<<<1, 256, 0, stream>>>(lossp, outf);
}